// Round 1
// baseline (123.587 us; speedup 1.0000x reference)
//
#include <hip/hip_runtime.h>
#include <hip/hip_bf16.h>

#define TWO_N  8192
#define N_HALF 4096
#define DIMS   256

typedef __bf16 bf16x8 __attribute__((ext_vector_type(8)));
typedef float  f32x4  __attribute__((ext_vector_type(4)));
typedef unsigned short ushort8v __attribute__((ext_vector_type(8)));

// raw v_exp_f32 (args here are bounded |x| <= ~3, no denormal/range handling needed)
__device__ __forceinline__ float fast_exp2(float x) {
#if __has_builtin(__builtin_amdgcn_exp2f)
    return __builtin_amdgcn_exp2f(x);
#else
    float r; asm("v_exp_f32 %0, %1" : "=v"(r) : "v"(x)); return r;
#endif
}

// ---------------------------------------------------------------------------
// Kernel 1: normalize rows of reps = cat([zjs, zis]), pre-scale by
// sqrt(2*log2(e)) so MFMA dot = (1/TEMP)*log2(e)*sim, and store in MFMA
// fragment-swizzled order: chunk = ((row/16)*8 + kk)*64 + quad*16 + (row%16),
// each chunk = 8 bf16 = elements k in [quad*8 + kk*32, +8) of that row.
// One 32-lane half-wave per row (8 rows / 256-thread block).
// ---------------------------------------------------------------------------
__global__ __launch_bounds__(256) void nrm_kernel(const float* __restrict__ zis,
                                                  const float* __restrict__ zjs,
                                                  unsigned short* __restrict__ swz)
{
    const int tid = threadIdx.x;
    const int l32 = tid & 31;
    const int row = blockIdx.x * 8 + (tid >> 5);
    const int k0  = l32 * 8;

    const float* src = (row < N_HALF) ? (zjs + (size_t)row * DIMS)
                                      : (zis + (size_t)(row - N_HALF) * DIMS);
    const float4 v0 = reinterpret_cast<const float4*>(src + k0)[0];
    const float4 v1 = reinterpret_cast<const float4*>(src + k0 + 4)[0];
    float ss = v0.x * v0.x + v0.y * v0.y + v0.z * v0.z + v0.w * v0.w
             + v1.x * v1.x + v1.y * v1.y + v1.z * v1.z + v1.w * v1.w;
#pragma unroll
    for (int m = 1; m < 32; m <<= 1) ss += __shfl_xor(ss, m, 64);
    // norms ~16 for N(0,1) rows; cosine eps path can never trigger
    const float inv = rsqrtf(ss) * 1.69864360045f;  // * sqrt(2*log2(e))

    const float vals[8] = {v0.x, v0.y, v0.z, v0.w, v1.x, v1.y, v1.z, v1.w};
    ushort8v o;
#pragma unroll
    for (int j = 0; j < 8; ++j) {
        __hip_bfloat16 b = __float2bfloat16(vals[j] * inv);
        o[j] = *reinterpret_cast<unsigned short*>(&b);
    }
    // kk = k0>>5 = l32>>2, quad = l32&3
    const int chunk = ((row >> 4) * 8 + (l32 >> 2)) * 64 + (l32 & 3) * 16 + (row & 15);
    *reinterpret_cast<ushort8v*>(swz + (size_t)chunk * 8) = o;
}

// ---------------------------------------------------------------------------
// Kernel 2: SYMMETRIC-HALF fused scaled-Gram (bf16 MFMA) + exp2 partial sums.
// sim is exactly symmetric (same bf16 fragments, same MFMA accumulation order
// for (i,j) and (j,i)), so only upper-triangle 256x256 tiles are computed:
// grid = 528 = 32*33/2 blocks, block -> (rg, cs) with cs >= rg.
// Each exp is credited to BOTH its row's lse-sum (register row accumulation,
// slot cs) and, for off-diagonal tiles, its column's lse-sum (per-iteration
// 16-lane butterfly reduce, slot 32 + rg*4 + wave). Positives only occur in
// tiles (rg, rg+16), rg<16 (all upper), and mirror exactly -> final factor 2.
// Partial-slot usage per row-group g is deterministic: row slots [g,32),
// col slots [32, 32+4g) -> no workspace zeroing needed.
// ---------------------------------------------------------------------------
__global__ __launch_bounds__(256, 2) void ntx_kernel(const __bf16* __restrict__ swz,
                                                     float* __restrict__ rowsum_part,
                                                     float* __restrict__ pos_part)
{
    const int lane = threadIdx.x & 63;
    const int wave = threadIdx.x >> 6;
    const int l15  = lane & 15;
    const int quad = lane >> 4;

    // upper-triangle tile index -> (rg, cs), cs >= rg
    int rg = 0, rem = blockIdx.x, width = 32;
    while (rem >= width) { rem -= width; ++rg; --width; }
    const int cs   = rg + rem;
    const bool diag = (rg == cs);

    const int wr0    = rg * 256 + wave * 64;
    const int c_base = cs * 256;
    const int p0     = wr0 ^ N_HALF;   // partner-row block (positives)

    // Hoist B (row) fragments: 4 groups of 16 rows, 8 K-chunks each.
    bf16x8 bfrag[4][8];
#pragma unroll
    for (int t = 0; t < 4; ++t) {
        const __bf16* bp = swz + (size_t)((wr0 >> 4) + t) * 4096 + lane * 8;
#pragma unroll
        for (int kk = 0; kk < 8; ++kk)
            bfrag[t][kk] = *reinterpret_cast<const bf16x8*>(bp + kk * 512);
    }

    const __bf16* abase = swz + (size_t)(cs * 16) * 4096 + lane * 8;

    float sum_exp[4] = {0.f, 0.f, 0.f, 0.f};
    float pos_acc = 0.f;

    bf16x8 a0[8], a1[8];
#pragma unroll
    for (int kk = 0; kk < 8; ++kk)
        a0[kk] = *reinterpret_cast<const bf16x8*>(abase + kk * 512);

    auto compute = [&](const bf16x8* af, int it) {
        const int cc0 = c_base + it * 16;
        f32x4 acc[4] = {{0.f, 0.f, 0.f, 0.f}, {0.f, 0.f, 0.f, 0.f},
                        {0.f, 0.f, 0.f, 0.f}, {0.f, 0.f, 0.f, 0.f}};
#pragma unroll
        for (int kk = 0; kk < 8; ++kk) {
#pragma unroll
            for (int t = 0; t < 4; ++t)
                acc[t] = __builtin_amdgcn_mfma_f32_16x16x32_bf16(
                    af[kk], bfrag[t][kk], acc[t], 0, 0, 0);
        }
        // acc = (1/TEMP)*log2(e)*sim ; row r = wr0+t*16+l15, col c = cc0+quad*4+j
        const bool special = (cc0 < wr0 + 64 && cc0 + 16 > wr0) ||
                             (cc0 < p0 + 64 && cc0 + 16 > p0);
        float pcol[4] = {0.f, 0.f, 0.f, 0.f};
        if (!special) {
#pragma unroll
            for (int t = 0; t < 4; ++t)
#pragma unroll
                for (int j = 0; j < 4; ++j) {
                    const float e = fast_exp2(acc[t][j]);
                    sum_exp[t] += e;
                    pcol[j] += e;
                }
        } else {
#pragma unroll
            for (int t = 0; t < 4; ++t) {
                const int r = wr0 + t * 16 + l15;
#pragma unroll
                for (int j = 0; j < 4; ++j) {
                    const int c = cc0 + quad * 4 + j;
                    const float e = fast_exp2(acc[t][j]);
                    const bool self = (c == r);                   // self-diag mask
                    sum_exp[t] += self ? 0.f : e;
                    pcol[j] += self ? 0.f : e;
                    if (c == (r ^ N_HALF)) pos_acc += acc[t][j];  // positive (scaled dot)
                }
            }
        }
        if (!diag) {
            // Column sums over this wave's 64 rows: reduce pcol[0..3] across
            // the 16 l15-lanes of each quad via packed butterfly (5 shfl).
            const int b1 = lane & 1, b2 = lane & 2;
            float a0v = b1 ? pcol[2] : pcol[0];
            float g0v = b1 ? pcol[0] : pcol[2];
            float a1v = b1 ? pcol[3] : pcol[1];
            float g1v = b1 ? pcol[1] : pcol[3];
            a0v += __shfl_xor(g0v, 1, 64);
            a1v += __shfl_xor(g1v, 1, 64);
            float k0v = b2 ? a1v : a0v;
            float k1v = b2 ? a0v : a1v;
            k0v += __shfl_xor(k1v, 2, 64);
            k0v += __shfl_xor(k0v, 4, 64);
            k0v += __shfl_xor(k0v, 8, 64);
            // lane l15 holds col (l15&1)*2 + ((l15>>1)&1) of its quad
            if (l15 < 4) {
                const int ccol = cc0 + quad * 4 + ((l15 & 1) * 2 + (l15 >> 1));
                rowsum_part[(size_t)(32 + rg * 4 + wave) * TWO_N + ccol] = k0v;
            }
        }
    };

    for (int it = 0; it < 16; it += 2) {
#pragma unroll
        for (int kk = 0; kk < 8; ++kk)
            a1[kk] = *reinterpret_cast<const bf16x8*>(abase + (size_t)(it + 1) * 4096 + kk * 512);
        compute(a0, it);
        if (it + 2 < 16) {
#pragma unroll
            for (int kk = 0; kk < 8; ++kk)
                a0[kk] = *reinterpret_cast<const bf16x8*>(abase + (size_t)(it + 2) * 4096 + kk * 512);
        }
        compute(a1, it + 1);
    }

    // Per-row partial: reduce over the 4 quads (col groups), one store per row.
#pragma unroll
    for (int t = 0; t < 4; ++t) {
        float s = sum_exp[t];
        s += __shfl_xor(s, 16, 64);
        s += __shfl_xor(s, 32, 64);
        if (lane < 16)
            rowsum_part[(size_t)cs * TWO_N + wr0 + t * 16 + lane] = s;
    }

    // Positive partial: every wave writes its slot (0 if no partner overlap).
#pragma unroll
    for (int m = 1; m < 64; m <<= 1) pos_acc += __shfl_xor(pos_acc, m, 64);
    if (lane == 0) pos_part[blockIdx.x * 4 + wave] = pos_acc;
}

// ---------------------------------------------------------------------------
// Kernel 3: per-row ln(sum of partials), minus 2*ln2 * positive partials
// (factor 2 = symmetric mirror of the positive diagonal), block-reduced.
// Row r (group g = r>>8) sums row slots [g,32) and col slots [32, 32+4g).
// Slot lists are wave-uniform (64 | 256), so no divergence.
// ---------------------------------------------------------------------------
__global__ __launch_bounds__(1024) void fin1_kernel(const float* __restrict__ rowsum_part,
                                                    const float* __restrict__ pos_part,
                                                    float* __restrict__ block_part)
{
    __shared__ float red[16];
    const int t = threadIdx.x;
    const int r = blockIdx.x * 1024 + t;
    const int g = r >> 8;
    float acc = 0.f;
    for (int s = g; s < 32; ++s)
        acc += rowsum_part[(size_t)s * TWO_N + r];
    const int ce = 32 + 4 * g;
    for (int s = 32; s < ce; ++s)
        acc += rowsum_part[(size_t)s * TWO_N + r];
    float v = logf(acc);
    if (t < 264)   // 528 blocks * 4 waves = 2112 pos partials = 8 * 264
        v -= 1.3862943611198906f * pos_part[blockIdx.x * 264 + t];  // 2*ln2
#pragma unroll
    for (int m = 1; m < 64; m <<= 1) v += __shfl_xor(v, m, 64);
    if ((t & 63) == 0) red[t >> 6] = v;
    __syncthreads();
    if (t == 0) {
        float s = 0.f;
#pragma unroll
        for (int w = 0; w < 16; ++w) s += red[w];
        block_part[blockIdx.x] = s;
    }
}

// ---------------------------------------------------------------------------
// Kernel 4: final scalar.
// ---------------------------------------------------------------------------
__global__ void fin2_kernel(const float* __restrict__ block_part, float* __restrict__ out)
{
    if (threadIdx.x == 0) {
        float s = 0.f;
#pragma unroll
        for (int i = 0; i < 8; ++i) s += block_part[i];
        out[0] = s / (float)TWO_N;
    }
}

// ---------------------------------------------------------------------------
extern "C" void kernel_launch(void* const* d_in, const int* in_sizes, int n_in,
                              void* d_out, int out_size, void* d_ws, size_t ws_size,
                              hipStream_t stream)
{
    const float* zis = (const float*)d_in[0];
    const float* zjs = (const float*)d_in[1];

    // ws: [0,4MB) swizzled bf16; then rowsum partials [160][8192] f32 (5MB,
    // slots 0..155 used); then pos partials [2112] (padded); then block parts.
    unsigned short* swz = (unsigned short*)d_ws;
    float* rowsum_part  = (float*)((char*)d_ws + (size_t)TWO_N * DIMS * sizeof(unsigned short));
    float* pos_part     = rowsum_part + (size_t)160 * TWO_N;
    float* block_part   = pos_part + 2560;

    nrm_kernel<<<TWO_N / 8, 256, 0, stream>>>(zis, zjs, swz);
    ntx_kernel<<<528, 256, 0, stream>>>((const __bf16*)swz, rowsum_part, pos_part);
    fin1_kernel<<<8, 1024, 0, stream>>>(rowsum_part, pos_part, block_part);
    fin2_kernel<<<1, 64, 0, stream>>>(block_part, (float*)d_out);
}

// Round 2
// 103.318 us; speedup vs baseline: 1.1962x; 1.1962x over previous
//
#include <hip/hip_runtime.h>
#include <hip/hip_bf16.h>

#define TWO_N  8192
#define N_HALF 4096
#define DIMS   256

typedef __bf16 bf16x8 __attribute__((ext_vector_type(8)));
typedef float  f32x4  __attribute__((ext_vector_type(4)));
typedef unsigned short ushort8v __attribute__((ext_vector_type(8)));

// raw v_exp_f32 (args here are bounded |x| <= ~3, no denormal/range handling needed)
__device__ __forceinline__ float fast_exp2(float x) {
#if __has_builtin(__builtin_amdgcn_exp2f)
    return __builtin_amdgcn_exp2f(x);
#else
    float r; asm("v_exp_f32 %0, %1" : "=v"(r) : "v"(x)); return r;
#endif
}

// ---------------------------------------------------------------------------
// Kernel 1: normalize rows of reps = cat([zjs, zis]), pre-scale by
// sqrt(2*log2(e)) so MFMA dot = (1/TEMP)*log2(e)*sim, and store in MFMA
// fragment-swizzled order: chunk = ((row/16)*8 + kk)*64 + quad*16 + (row%16),
// each chunk = 8 bf16 = elements k in [quad*8 + kk*32, +8) of that row.
// One 32-lane half-wave per row (8 rows / 256-thread block).
// ---------------------------------------------------------------------------
__global__ __launch_bounds__(256) void nrm_kernel(const float* __restrict__ zis,
                                                  const float* __restrict__ zjs,
                                                  unsigned short* __restrict__ swz)
{
    const int tid = threadIdx.x;
    const int l32 = tid & 31;
    const int row = blockIdx.x * 8 + (tid >> 5);
    const int k0  = l32 * 8;

    const float* src = (row < N_HALF) ? (zjs + (size_t)row * DIMS)
                                      : (zis + (size_t)(row - N_HALF) * DIMS);
    const float4 v0 = reinterpret_cast<const float4*>(src + k0)[0];
    const float4 v1 = reinterpret_cast<const float4*>(src + k0 + 4)[0];
    float ss = v0.x * v0.x + v0.y * v0.y + v0.z * v0.z + v0.w * v0.w
             + v1.x * v1.x + v1.y * v1.y + v1.z * v1.z + v1.w * v1.w;
#pragma unroll
    for (int m = 1; m < 32; m <<= 1) ss += __shfl_xor(ss, m, 64);
    // norms ~16 for N(0,1) rows; cosine eps path can never trigger
    const float inv = rsqrtf(ss) * 1.69864360045f;  // * sqrt(2*log2(e))

    const float vals[8] = {v0.x, v0.y, v0.z, v0.w, v1.x, v1.y, v1.z, v1.w};
    ushort8v o;
#pragma unroll
    for (int j = 0; j < 8; ++j) {
        __hip_bfloat16 b = __float2bfloat16(vals[j] * inv);
        o[j] = *reinterpret_cast<unsigned short*>(&b);
    }
    // kk = k0>>5 = l32>>2, quad = l32&3
    const int chunk = ((row >> 4) * 8 + (l32 >> 2)) * 64 + (l32 & 3) * 16 + (row & 15);
    *reinterpret_cast<ushort8v*>(swz + (size_t)chunk * 8) = o;
}

// ---------------------------------------------------------------------------
// Kernel 2: SYMMETRIC-HALF fused scaled-Gram (bf16 MFMA) + exp2 partial sums.
// Only upper-triangle 256x256 tiles are computed (sim is exactly symmetric:
// same bf16 fragments, same MFMA accumulation order for (i,j) and (j,i)).
// Grid = 528: idx 0..495 -> off-diag tiles (rg<cs), idx 496..527 -> the 32
// diag tiles (cheaper: no col-credit) so the post-round stragglers are cheap.
// Row-credit: register accumulation, slot cs.  Col-credit (off-diag only):
// per-iteration per-lane ds_write into colbuf[256 col][64 slot=wave*16+l15],
// one barrier + float4 reduce per tile at the end -> slot 32+rg.
// No cross-lane chains in the hot loop; single A buffer + LDS col-sum keeps
// VGPRs ~200 (round-1's butterfly + dbuf version likely spilled at 256 cap).
// Slot usage per row-group g is deterministic: row slots [g,32), col slots
// [32, 32+g) -> fin1 always sums exactly 32 slots; no workspace zeroing.
// ---------------------------------------------------------------------------
__global__ __launch_bounds__(256, 2) void ntx_kernel(const __bf16* __restrict__ swz,
                                                     float* __restrict__ rowsum_part,
                                                     float* __restrict__ pos_part)
{
    __shared__ float colbuf[256 * 64];   // 64 KB: [col][wave*16+l15]

    const int lane = threadIdx.x & 63;
    const int wave = threadIdx.x >> 6;
    const int l15  = lane & 15;
    const int quad = lane >> 4;

    // tile index -> (rg, cs)
    int rg, cs;
    if ((int)blockIdx.x >= 496) {
        rg = cs = blockIdx.x - 496;            // diagonal tiles last
    } else {
        int rem = blockIdx.x, width = 31;      // off-diag count in row rg: 31-rg
        rg = 0;
        while (rem >= width) { rem -= width; ++rg; --width; }
        cs = rg + 1 + rem;
    }
    const bool diag = (rg == cs);

    const int wr0    = rg * 256 + wave * 64;
    const int c_base = cs * 256;
    const int p0     = wr0 ^ N_HALF;   // partner-row block (positives)

    // Hoist B (row) fragments: 4 groups of 16 rows, 8 K-chunks each. (128 VGPR)
    bf16x8 bfrag[4][8];
#pragma unroll
    for (int t = 0; t < 4; ++t) {
        const __bf16* bp = swz + (size_t)((wr0 >> 4) + t) * 4096 + lane * 8;
#pragma unroll
        for (int kk = 0; kk < 8; ++kk)
            bfrag[t][kk] = *reinterpret_cast<const bf16x8*>(bp + kk * 512);
    }

    const __bf16* abase = swz + (size_t)(cs * 16) * 4096 + lane * 8;

    float sum_exp[4] = {0.f, 0.f, 0.f, 0.f};
    float pos_acc = 0.f;

    for (int it = 0; it < 16; ++it) {
        bf16x8 a[8];
#pragma unroll
        for (int kk = 0; kk < 8; ++kk)
            a[kk] = *reinterpret_cast<const bf16x8*>(abase + (size_t)it * 4096 + kk * 512);

        const int cc0 = c_base + it * 16;
        f32x4 acc[4] = {{0.f, 0.f, 0.f, 0.f}, {0.f, 0.f, 0.f, 0.f},
                        {0.f, 0.f, 0.f, 0.f}, {0.f, 0.f, 0.f, 0.f}};
#pragma unroll
        for (int kk = 0; kk < 8; ++kk) {
#pragma unroll
            for (int t = 0; t < 4; ++t)
                acc[t] = __builtin_amdgcn_mfma_f32_16x16x32_bf16(
                    a[kk], bfrag[t][kk], acc[t], 0, 0, 0);
        }
        // acc = (1/TEMP)*log2(e)*sim ; row r = wr0+t*16+l15, col c = cc0+quad*4+j
        const bool special = (cc0 < wr0 + 64 && cc0 + 16 > wr0) ||
                             (cc0 < p0 + 64 && cc0 + 16 > p0);
        float pcol[4] = {0.f, 0.f, 0.f, 0.f};
        if (!special) {
#pragma unroll
            for (int t = 0; t < 4; ++t)
#pragma unroll
                for (int j = 0; j < 4; ++j) {
                    const float e = fast_exp2(acc[t][j]);
                    sum_exp[t] += e;
                    pcol[j] += e;
                }
        } else {
#pragma unroll
            for (int t = 0; t < 4; ++t) {
                const int r = wr0 + t * 16 + l15;
#pragma unroll
                for (int j = 0; j < 4; ++j) {
                    const int c = cc0 + quad * 4 + j;
                    const float e = fast_exp2(acc[t][j]);
                    const bool self = (c == r);                   // self-diag mask
                    sum_exp[t] += self ? 0.f : e;
                    pcol[j] += self ? 0.f : e;
                    if (c == (r ^ N_HALF)) pos_acc += acc[t][j];  // positive (scaled dot)
                }
            }
        }
        if (!diag) {
            // col-credit partials: fire-and-forget LDS writes, no cross-lane ops
            const int cbase_l = (it * 16 + quad * 4) * 64 + wave * 16 + l15;
#pragma unroll
            for (int j = 0; j < 4; ++j)
                colbuf[cbase_l + j * 64] = pcol[j];
        }
    }

    // Per-row partial: reduce over the 4 quads (col groups), one store per row.
#pragma unroll
    for (int t = 0; t < 4; ++t) {
        float s = sum_exp[t];
        s += __shfl_xor(s, 16, 64);
        s += __shfl_xor(s, 32, 64);
        if (lane < 16)
            rowsum_part[(size_t)cs * TWO_N + wr0 + t * 16 + lane] = s;
    }

    // Positive partial: every wave writes its slot (0 if no partner overlap).
#pragma unroll
    for (int m = 1; m < 64; m <<= 1) pos_acc += __shfl_xor(pos_acc, m, 64);
    if (lane == 0) pos_part[blockIdx.x * 4 + wave] = pos_acc;

    // Column sums for the whole tile (off-diag only): thread t owns col t,
    // sums its 64 slots (16 x float4, l15-rotated start to spread banks).
    if (!diag) {
        __syncthreads();
        const int t = threadIdx.x;
        const float4* cb = reinterpret_cast<const float4*>(colbuf + t * 64);
        float4 s4 = {0.f, 0.f, 0.f, 0.f};
#pragma unroll
        for (int i = 0; i < 16; ++i) {
            const float4 v = cb[((t & 15) + i) & 15];
            s4.x += v.x; s4.y += v.y; s4.z += v.z; s4.w += v.w;
        }
        rowsum_part[(size_t)(32 + rg) * TWO_N + cs * 256 + t] =
            (s4.x + s4.y) + (s4.z + s4.w);
    }
}

// ---------------------------------------------------------------------------
// Kernel 3: per-row ln(sum of partials), minus 2*ln2 * positive partials
// (factor 2 = symmetric mirror of the positive diagonal), block-reduced.
// Row r (group g = r>>8) sums row slots [g,32) and col slots [32, 32+g)
// -> exactly 32 slot reads per row. Slot bounds are wave-uniform (64 | 256).
// ---------------------------------------------------------------------------
__global__ __launch_bounds__(1024) void fin1_kernel(const float* __restrict__ rowsum_part,
                                                    const float* __restrict__ pos_part,
                                                    float* __restrict__ block_part)
{
    __shared__ float red[16];
    const int t = threadIdx.x;
    const int r = blockIdx.x * 1024 + t;
    const int g = r >> 8;
    float acc = 0.f;
    for (int s = g; s < 32; ++s)
        acc += rowsum_part[(size_t)s * TWO_N + r];
    const int ce = 32 + g;
    for (int s = 32; s < ce; ++s)
        acc += rowsum_part[(size_t)s * TWO_N + r];
    float v = logf(acc);
    if (r < 2112)   // 528 blocks * 4 waves of pos partials
        v -= 1.3862943611198906f * pos_part[r];  // 2*ln2 (mirror factor)
#pragma unroll
    for (int m = 1; m < 64; m <<= 1) v += __shfl_xor(v, m, 64);
    if ((t & 63) == 0) red[t >> 6] = v;
    __syncthreads();
    if (t == 0) {
        float s = 0.f;
#pragma unroll
        for (int w = 0; w < 16; ++w) s += red[w];
        block_part[blockIdx.x] = s;
    }
}

// ---------------------------------------------------------------------------
// Kernel 4: final scalar.
// ---------------------------------------------------------------------------
__global__ void fin2_kernel(const float* __restrict__ block_part, float* __restrict__ out)
{
    if (threadIdx.x == 0) {
        float s = 0.f;
#pragma unroll
        for (int i = 0; i < 8; ++i) s += block_part[i];
        out[0] = s / (float)TWO_N;
    }
}

// ---------------------------------------------------------------------------
extern "C" void kernel_launch(void* const* d_in, const int* in_sizes, int n_in,
                              void* d_out, int out_size, void* d_ws, size_t ws_size,
                              hipStream_t stream)
{
    const float* zis = (const float*)d_in[0];
    const float* zjs = (const float*)d_in[1];

    // ws: [0,4MB) swizzled bf16; then rowsum partials [64][8192] f32 (2MB,
    // row slots 0..31, col slots 32..62); then pos partials [2112] (padded);
    // then block partials [8].
    unsigned short* swz = (unsigned short*)d_ws;
    float* rowsum_part  = (float*)((char*)d_ws + (size_t)TWO_N * DIMS * sizeof(unsigned short));
    float* pos_part     = rowsum_part + (size_t)64 * TWO_N;
    float* block_part   = pos_part + 2560;

    nrm_kernel<<<TWO_N / 8, 256, 0, stream>>>(zis, zjs, swz);
    ntx_kernel<<<528, 256, 0, stream>>>((const __bf16*)swz, rowsum_part, pos_part);
    fin1_kernel<<<8, 1024, 0, stream>>>(rowsum_part, pos_part, block_part);
    fin2_kernel<<<1, 64, 0, stream>>>(block_part, (float*)d_out);
}

// Round 3
// 98.828 us; speedup vs baseline: 1.2505x; 1.0454x over previous
//
#include <hip/hip_runtime.h>
#include <hip/hip_bf16.h>

#define TWO_N  8192
#define N_HALF 4096
#define DIMS   256

typedef __bf16 bf16x8 __attribute__((ext_vector_type(8)));
typedef float  f32x4  __attribute__((ext_vector_type(4)));
typedef unsigned short ushort8v __attribute__((ext_vector_type(8)));

// raw v_exp_f32 (args here are bounded |x| <= ~3, no denormal/range handling needed)
__device__ __forceinline__ float fast_exp2(float x) {
#if __has_builtin(__builtin_amdgcn_exp2f)
    return __builtin_amdgcn_exp2f(x);
#else
    float r; asm("v_exp_f32 %0, %1" : "=v"(r) : "v"(x)); return r;
#endif
}

// ---------------------------------------------------------------------------
// Kernel 1: normalize rows of reps = cat([zjs, zis]), pre-scale by
// sqrt(2*log2(e)) so MFMA dot = (1/TEMP)*log2(e)*sim, and store in MFMA
// fragment-swizzled order: chunk = ((row/16)*8 + kk)*64 + quad*16 + (row%16),
// each chunk = 8 bf16 = elements k in [quad*8 + kk*32, +8) of that row.
// ---------------------------------------------------------------------------
__global__ __launch_bounds__(256) void nrm_kernel(const float* __restrict__ zis,
                                                  const float* __restrict__ zjs,
                                                  unsigned short* __restrict__ swz)
{
    const int tid = threadIdx.x;
    const int l32 = tid & 31;
    const int row = blockIdx.x * 8 + (tid >> 5);
    const int k0  = l32 * 8;

    const float* src = (row < N_HALF) ? (zjs + (size_t)row * DIMS)
                                      : (zis + (size_t)(row - N_HALF) * DIMS);
    const float4 v0 = reinterpret_cast<const float4*>(src + k0)[0];
    const float4 v1 = reinterpret_cast<const float4*>(src + k0 + 4)[0];
    float ss = v0.x * v0.x + v0.y * v0.y + v0.z * v0.z + v0.w * v0.w
             + v1.x * v1.x + v1.y * v1.y + v1.z * v1.z + v1.w * v1.w;
#pragma unroll
    for (int m = 1; m < 32; m <<= 1) ss += __shfl_xor(ss, m, 64);
    const float inv = rsqrtf(ss) * 1.69864360045f;  // * sqrt(2*log2(e))

    const float vals[8] = {v0.x, v0.y, v0.z, v0.w, v1.x, v1.y, v1.z, v1.w};
    ushort8v o;
#pragma unroll
    for (int j = 0; j < 8; ++j) {
        __hip_bfloat16 b = __float2bfloat16(vals[j] * inv);
        o[j] = *reinterpret_cast<unsigned short*>(&b);
    }
    const int chunk = ((row >> 4) * 8 + (l32 >> 2)) * 64 + (l32 & 3) * 16 + (row & 15);
    *reinterpret_cast<ushort8v*>(swz + (size_t)chunk * 8) = o;
}

// ---------------------------------------------------------------------------
// Kernel 2: SYMMETRIC-HALF Gram. Grid = 496 off-diagonal 256x256 tiles ONLY
// (<= 512 co-resident slots at 2 blocks/CU -> ONE dispatch round; round-2's
// 528-block grid needed 2 rounds, erasing the symmetry win).
// The 32 diagonal tiles are folded into off-diag blocks as side tasks:
//   dg<=15 "strip": block (dg, cs<=dg+16) computes sim[256 rows dg][16 cols
//     it0=cs-dg-1 of dg] after the main loop (bfrag reused, extra 8KB A),
//     credited as COL-credit -> slot dg (each diag col exactly once).
//   dg>=16 "chunk": block (rg<=15, dg) computes sim[16 rows r0=rg of dg]
//     [256 cols of dg] inside the main loop (A-stream reused, extra 8KB B in
//     LDS), 4 its per wave (it>>2==wave), ROW-credit -> slot dg.
// fin1's 32-slot pattern is unchanged: slot g = diag, g+1..31 row, 32..32+g col.
// Also: A double-buffer restored; colbuf writes XOR-swizzled (2-way conflicts).
// ---------------------------------------------------------------------------
__global__ __launch_bounds__(256, 2) void ntx_kernel(const __bf16* __restrict__ swz,
                                                     float* __restrict__ rowsum_part,
                                                     float* __restrict__ pos_part)
{
    __shared__ float  colbuf[256 * 64];   // 64 KB
    __shared__ __bf16 chunkB[4096];       // 8 KB: 16 rows x 256 K, swz layout
    __shared__ float  cross[4][16];

    const int tid  = threadIdx.x;
    const int lane = tid & 63;
    const int wave = tid >> 6;
    const int l15  = lane & 15;
    const int quad = lane >> 4;

    // off-diag decode: row rg has 31-rg tiles
    int rg = 0, rem = blockIdx.x, width = 31;
    while (rem >= width) { rem -= width; ++rg; --width; }
    const int cs = rg + 1 + rem;

    const bool chunk_on = (rg < 16) && (cs >= 16);
    const bool strip_on = (rg < 16) && (cs - rg <= 16);

    // stage chunkB (16 rows r0=rg of group cs, full K) into LDS
    if (chunk_on) {
        const ushort8v* src = reinterpret_cast<const ushort8v*>(swz + (size_t)(cs * 16 + rg) * 4096);
        reinterpret_cast<ushort8v*>(chunkB)[tid]       = src[tid];
        reinterpret_cast<ushort8v*>(chunkB)[tid + 256] = src[tid + 256];
    }

    const int wr0    = rg * 256 + wave * 64;
    const int c_base = cs * 256;
    const int p0     = wr0 ^ N_HALF;   // partner-row block (positives)

    // Hoist B (row) fragments: 4 groups of 16 rows, 8 K-chunks each. (128 VGPR)
    bf16x8 bfrag[4][8];
#pragma unroll
    for (int t = 0; t < 4; ++t) {
        const __bf16* bp = swz + (size_t)((wr0 >> 4) + t) * 4096 + lane * 8;
#pragma unroll
        for (int kk = 0; kk < 8; ++kk)
            bfrag[t][kk] = *reinterpret_cast<const bf16x8*>(bp + kk * 512);
    }

    const __bf16* abase = swz + (size_t)(cs * 16) * 4096 + lane * 8;

    float sum_exp[4] = {0.f, 0.f, 0.f, 0.f};
    float pos_acc  = 0.f;
    float chunkacc = 0.f;

    __syncthreads();   // chunkB ready

    bf16x8 a0[8], a1[8];
#pragma unroll
    for (int kk = 0; kk < 8; ++kk)
        a0[kk] = *reinterpret_cast<const bf16x8*>(abase + kk * 512);

    auto compute = [&](const bf16x8* af, int it) {
        const int cc0 = c_base + it * 16;
        f32x4 acc[4] = {{0.f, 0.f, 0.f, 0.f}, {0.f, 0.f, 0.f, 0.f},
                        {0.f, 0.f, 0.f, 0.f}, {0.f, 0.f, 0.f, 0.f}};
#pragma unroll
        for (int kk = 0; kk < 8; ++kk) {
#pragma unroll
            for (int t = 0; t < 4; ++t)
                acc[t] = __builtin_amdgcn_mfma_f32_16x16x32_bf16(
                    af[kk], bfrag[t][kk], acc[t], 0, 0, 0);
        }
        // row r = wr0+t*16+l15, col c = cc0+quad*4+j. Off-diag tile: self-diag
        // impossible; only positives (tile (g,g+16)) are special.
        const bool special = (cc0 < p0 + 64 && cc0 + 16 > p0);
        float pcol[4];
        if (!special) {
#pragma unroll
            for (int j = 0; j < 4; ++j) {
                float s = 0.f;
#pragma unroll
                for (int t = 0; t < 4; ++t) {
                    const float e = fast_exp2(acc[t][j]);
                    sum_exp[t] += e;
                    s += e;
                }
                pcol[j] = s;
            }
        } else {
#pragma unroll
            for (int j = 0; j < 4; ++j) pcol[j] = 0.f;
#pragma unroll
            for (int t = 0; t < 4; ++t) {
                const int r = wr0 + t * 16 + l15;
#pragma unroll
                for (int j = 0; j < 4; ++j) {
                    const int c = cc0 + quad * 4 + j;
                    const float e = fast_exp2(acc[t][j]);
                    sum_exp[t] += e;
                    pcol[j] += e;
                    if (c == (r ^ N_HALF)) pos_acc += acc[t][j];  // positive (scaled dot)
                }
            }
        }
        // col-credit partials, XOR-swizzled (bank bits 4-5 ^= quad) -> 2-way
#pragma unroll
        for (int j = 0; j < 4; ++j) {
            const int cl = it * 16 + quad * 4 + j;
            colbuf[cl * 64 + ((wave * 16 + l15) ^ ((cl & 12) << 2))] = pcol[j];
        }
        // diag chunk side-task: 16 rows (r0=rg) of group cs x current 16 cols
        if (chunk_on && (it >> 2) == wave) {
            f32x4 accC = {0.f, 0.f, 0.f, 0.f};
#pragma unroll
            for (int kp = 0; kp < 4; ++kp) {
                const bf16x8 b0 = *reinterpret_cast<const bf16x8*>(chunkB + (2 * kp)     * 512 + lane * 8);
                const bf16x8 b1 = *reinterpret_cast<const bf16x8*>(chunkB + (2 * kp + 1) * 512 + lane * 8);
                accC = __builtin_amdgcn_mfma_f32_16x16x32_bf16(af[2 * kp],     b0, accC, 0, 0, 0);
                accC = __builtin_amdgcn_mfma_f32_16x16x32_bf16(af[2 * kp + 1], b1, accC, 0, 0, 0);
            }
            // entry: row cr = cs*256 + rg*16 + l15, col c = cc0 + quad*4 + j
#pragma unroll
            for (int j = 0; j < 4; ++j) {
                const bool self = (it == rg) && (quad * 4 + j == l15);
                chunkacc += self ? 0.f : fast_exp2(accC[j]);
            }
        }
    };

    for (int it = 0; it < 16; it += 2) {
#pragma unroll
        for (int kk = 0; kk < 8; ++kk)
            a1[kk] = *reinterpret_cast<const bf16x8*>(abase + (size_t)(it + 1) * 4096 + kk * 512);
        compute(a0, it);
        if (it + 2 < 16) {
#pragma unroll
            for (int kk = 0; kk < 8; ++kk)
                a0[kk] = *reinterpret_cast<const bf16x8*>(abase + (size_t)(it + 2) * 4096 + kk * 512);
        }
        compute(a1, it + 1);
    }

    // Per-row partial: reduce over the 4 quads, one store per row -> slot cs.
#pragma unroll
    for (int t = 0; t < 4; ++t) {
        float s = sum_exp[t];
        s += __shfl_xor(s, 16, 64);
        s += __shfl_xor(s, 32, 64);
        if (lane < 16)
            rowsum_part[(size_t)cs * TWO_N + wr0 + t * 16 + lane] = s;
    }

    // Positive partial: every wave writes its slot (0 if no partner overlap).
#pragma unroll
    for (int m = 1; m < 64; m <<= 1) pos_acc += __shfl_xor(pos_acc, m, 64);
    if (lane == 0) pos_part[blockIdx.x * 4 + wave] = pos_acc;

    // chunk: reduce over quads -> per-(wave,l15) partial; stash for cross-wave
    if (chunk_on) {
        float s = chunkacc;
        s += __shfl_xor(s, 16, 64);
        s += __shfl_xor(s, 32, 64);
        if (quad == 0) cross[wave][l15] = s;
    }
    __syncthreads();

    // Main tile col-credit: thread t owns col t, sums 64 slots -> slot 32+rg.
    {
        const float4* cb = reinterpret_cast<const float4*>(colbuf + tid * 64);
        float4 s4 = {0.f, 0.f, 0.f, 0.f};
#pragma unroll
        for (int i = 0; i < 16; ++i) {
            const float4 v = cb[i ^ (tid & 12)];
            s4.x += v.x; s4.y += v.y; s4.z += v.z; s4.w += v.w;
        }
        rowsum_part[(size_t)(32 + rg) * TWO_N + c_base + tid] =
            (s4.x + s4.y) + (s4.z + s4.w);
    }
    // chunk final: rows cs*256 + rg*16 + t -> diag slot cs
    if (chunk_on && tid < 16) {
        const float s = cross[0][tid] + cross[1][tid] + cross[2][tid] + cross[3][tid];
        rowsum_part[(size_t)cs * TWO_N + cs * 256 + rg * 16 + tid] = s;
    }

    // strip side-task: sim[256 rows of rg][16 cols it0 of rg], col-credit.
    if (strip_on) {
        __syncthreads();   // colbuf free for reuse
        const int it0 = cs - rg - 1;
        const __bf16* sb = swz + (size_t)(rg * 16 + it0) * 4096 + lane * 8;
        bf16x8 as[8];
#pragma unroll
        for (int kk = 0; kk < 8; ++kk)
            as[kk] = *reinterpret_cast<const bf16x8*>(sb + kk * 512);
        f32x4 aS[4] = {{0.f, 0.f, 0.f, 0.f}, {0.f, 0.f, 0.f, 0.f},
                       {0.f, 0.f, 0.f, 0.f}, {0.f, 0.f, 0.f, 0.f}};
#pragma unroll
        for (int kk = 0; kk < 8; ++kk) {
#pragma unroll
            for (int t = 0; t < 4; ++t)
                aS[t] = __builtin_amdgcn_mfma_f32_16x16x32_bf16(
                    as[kk], bfrag[t][kk], aS[t], 0, 0, 0);
        }
        // entry: row = rg*256 + wave*64 + t*16 + l15, col-within = it0*16+quad*4+j
#pragma unroll
        for (int j = 0; j < 4; ++j) {
            float s = 0.f;
#pragma unroll
            for (int t = 0; t < 4; ++t) {
                const bool self = ((wave * 4 + t) == it0) && (l15 == quad * 4 + j);
                s += self ? 0.f : fast_exp2(aS[t][j]);
            }
            colbuf[(quad * 4 + j) * 64 + wave * 16 + l15] = s;
        }
        __syncthreads();
        if (tid < 16) {
            const float4* cb = reinterpret_cast<const float4*>(colbuf + tid * 64);
            float4 s4 = {0.f, 0.f, 0.f, 0.f};
#pragma unroll
            for (int i = 0; i < 16; ++i) {
                const float4 v = cb[i];
                s4.x += v.x; s4.y += v.y; s4.z += v.z; s4.w += v.w;
            }
            rowsum_part[(size_t)rg * TWO_N + rg * 256 + it0 * 16 + tid] =
                (s4.x + s4.y) + (s4.z + s4.w);
        }
    }
}

// ---------------------------------------------------------------------------
// Kernel 3: per-row ln(sum of partials) - 2*ln2 * positive partials.
// Row r (g=r>>8): row+diag slots [g,32) and col slots [32,32+g) -> 32 reads.
// ---------------------------------------------------------------------------
__global__ __launch_bounds__(1024) void fin1_kernel(const float* __restrict__ rowsum_part,
                                                    const float* __restrict__ pos_part,
                                                    float* __restrict__ block_part)
{
    __shared__ float red[16];
    const int t = threadIdx.x;
    const int r = blockIdx.x * 1024 + t;
    const int g = r >> 8;
    float acc = 0.f;
    for (int s = g; s < 32; ++s)
        acc += rowsum_part[(size_t)s * TWO_N + r];
    const int ce = 32 + g;
    for (int s = 32; s < ce; ++s)
        acc += rowsum_part[(size_t)s * TWO_N + r];
    float v = logf(acc);
    if (r < 1984)   // 496 blocks * 4 waves of pos partials
        v -= 1.3862943611198906f * pos_part[r];  // 2*ln2 (mirror factor)
#pragma unroll
    for (int m = 1; m < 64; m <<= 1) v += __shfl_xor(v, m, 64);
    if ((t & 63) == 0) red[t >> 6] = v;
    __syncthreads();
    if (t == 0) {
        float s = 0.f;
#pragma unroll
        for (int w = 0; w < 16; ++w) s += red[w];
        block_part[blockIdx.x] = s;
    }
}

// ---------------------------------------------------------------------------
__global__ void fin2_kernel(const float* __restrict__ block_part, float* __restrict__ out)
{
    if (threadIdx.x == 0) {
        float s = 0.f;
#pragma unroll
        for (int i = 0; i < 8; ++i) s += block_part[i];
        out[0] = s / (float)TWO_N;
    }
}

// ---------------------------------------------------------------------------
extern "C" void kernel_launch(void* const* d_in, const int* in_sizes, int n_in,
                              void* d_out, int out_size, void* d_ws, size_t ws_size,
                              hipStream_t stream)
{
    const float* zis = (const float*)d_in[0];
    const float* zjs = (const float*)d_in[1];

    // ws: [0,4MB) swizzled bf16; [4MB,+2MB) rowsum partials [64][8192]
    // (slots 0..31 row+diag, 32..62 col); then pos partials [1984] (pad 2048);
    // then block partials [8].
    unsigned short* swz = (unsigned short*)d_ws;
    float* rowsum_part  = (float*)((char*)d_ws + (size_t)TWO_N * DIMS * sizeof(unsigned short));
    float* pos_part     = rowsum_part + (size_t)64 * TWO_N;
    float* block_part   = pos_part + 2048;

    nrm_kernel<<<TWO_N / 8, 256, 0, stream>>>(zis, zjs, swz);
    ntx_kernel<<<496, 256, 0, stream>>>((const __bf16*)swz, rowsum_part, pos_part);
    fin1_kernel<<<8, 1024, 0, stream>>>(rowsum_part, pos_part, block_part);
    fin2_kernel<<<1, 64, 0, stream>>>(block_part, (float*)d_out);
}